// Round 14
// baseline (126.646 us; speedup 1.0000x reference)
//
#include <hip/hip_runtime.h>

// ---- problem constants (fixed by reference setup_inputs) ----
constexpr int B_  = 32;
constexpr int Na  = 512;
constexpr int Nv  = 256;
constexpr int D   = 384;

constexpr int NK2 = D / 64;    // 6 k-chunks of 64 (one scaled MFMA each)

// fp8 operand regions, one 32-row group x 384 k = 12 KB per group.
// UNIFIED layout both sides (R14: V reverted to A-style — the lane-32B V
// packing cost K1 ~10us of scatter writes and bought K2 nothing, since the
// V load is two separate dwordx4 either way):
//   unit kc (1 KB): byte = h2*512 + r*16 + j holding
//   value[row r][k = kc*32 + h2*16 + j]; MFMA lane l reads 16 B at l*16
//   (r = l&31, h2 = l>>5). K=64 operand = unit 2q2 (regs0-3) + unit 2q2+1
//   (regs4-7): two 16B loads at +0 / +1024.
// The (lane,byte)->k packing is IDENTICAL for A-slot and B-slot operands,
// so the contraction is exact under operand swap; scales = 1.0 (e8m0 0x7F)
// make the scaled MFMA numerically identical to non-scaled fp8.
constexpr int AGROUPS = B_ * 16;   // 512 groups (bi*16+rg), rows linear
constexpr int BGROUPS = B_ * 8;    // 256 groups (bj*8+cg), rows linear
constexpr size_t GROUP_BYTES = 12 * 1024;
constexpr int SCALE_ONE = 0x7F7F7F7F;   // e8m0 127 = 2^0 in every byte

typedef int   int4v    __attribute__((ext_vector_type(4)));
typedef int   int8v    __attribute__((ext_vector_type(8)));
typedef float floatx16 __attribute__((ext_vector_type(16)));

// 16B-per-lane async global->LDS (lane i writes LDS slot base + i*16)
__device__ __forceinline__ void async_load16(const void* g, void* l) {
    __builtin_amdgcn_global_load_lds(
        (const __attribute__((address_space(1))) unsigned int*)g,
        (__attribute__((address_space(3))) unsigned int*)l,
        16, 0, 0);
}

// asm-volatile global load: UNSINKABLE by the scheduler (plain C++ "prefetch"
// loads get sunk to their use — R3's VGPR=104 proved it). Completion is NOT
// compiler-tracked: consumers sit after an explicit counted s_waitcnt +
// sched_barrier(0) fence (rule #18).
#define VLOAD16(dst, ptr) \
    asm volatile("global_load_dwordx4 %0, %1, off" : "=v"(dst) : "v"(ptr))

// ---- K1: zero output + fp32 -> fp8(e4m3 OCP) conversion, BOTH sides coalesced ----
// Single store path: per pass, a wave's 64 16-B stores tile 16 full 64-B
// lines (r*16 contiguous within each (kc,h2) slot). 3x k-split grid for TLP.
__global__ void convert_fp8_kernel(const float* __restrict__ a, const float* __restrict__ v,
                                   unsigned char* __restrict__ a8,
                                   unsigned char* __restrict__ b8,
                                   float* __restrict__ out) {
    int gid = blockIdx.x * blockDim.x + threadIdx.x;
    if (gid < B_ * B_) out[gid] = 0.0f;    // d_out is poisoned before every launch

    const int blk = blockIdx.x / 3;        // group 0..767
    const int p   = blockIdx.x % 3;        // k-third 0..2
    const float* src;
    unsigned char* dst;
    if (blk < AGROUPS) {                       // A rows are linear: group*32 + r
        src = a + (size_t)blk * 32 * D;
        dst = a8 + (size_t)blk * GROUP_BYTES;
    } else {
        int b2 = blk - AGROUPS;
        src = v + (size_t)b2 * 32 * D;
        dst = b8 + (size_t)b2 * GROUP_BYTES;
    }
    const int t = threadIdx.x;
    const int r = t >> 3, q = t & 7;

    int k0 = p * 128 + q * 16;
    const float4* s4 = (const float4*)(src + (size_t)r * D + k0);
    float4 f0 = s4[0], f1 = s4[1], f2 = s4[2], f3 = s4[3];
    int w0 = 0, w1 = 0, w2 = 0, w3 = 0;
    w0 = __builtin_amdgcn_cvt_pk_fp8_f32(f0.x, f0.y, w0, false);
    w0 = __builtin_amdgcn_cvt_pk_fp8_f32(f0.z, f0.w, w0, true);
    w1 = __builtin_amdgcn_cvt_pk_fp8_f32(f1.x, f1.y, w1, false);
    w1 = __builtin_amdgcn_cvt_pk_fp8_f32(f1.z, f1.w, w1, true);
    w2 = __builtin_amdgcn_cvt_pk_fp8_f32(f2.x, f2.y, w2, false);
    w2 = __builtin_amdgcn_cvt_pk_fp8_f32(f2.z, f2.w, w2, true);
    w3 = __builtin_amdgcn_cvt_pk_fp8_f32(f3.x, f3.y, w3, false);
    w3 = __builtin_amdgcn_cvt_pk_fp8_f32(f3.z, f3.w, w3, true);
    int kc = k0 >> 5;
    int h2 = (k0 >> 4) & 1;
    int4v o = { w0, w1, w2, w3 };
    *(int4v*)(dst + (size_t)kc * 1024 + h2 * 512 + r * 16) = o;
}

// sum of exp2(a[i] * 1/(tau*ln2)) over one accumulator, pairwise tree.
// RAW v_exp_f32: |x| <= ~60, inside the exact range of the HW instruction.
__device__ __forceinline__ float expsum16(floatx16 a) {
    constexpr float INV_TAU_LN2 = 0.7213475204444817f;  // 1/(tau*ln2), tau=2
    float e[16];
    #pragma unroll
    for (int i = 0; i < 16; ++i)
        e[i] = __builtin_amdgcn_exp2f(a[i] * INV_TAU_LN2);
    float t0 = (e[0] + e[1])  + (e[2] + e[3]);
    float t1 = (e[4] + e[5])  + (e[6] + e[7]);
    float t2 = (e[8] + e[9])  + (e[10] + e[11]);
    float t3 = (e[12] + e[13]) + (e[14] + e[15]);
    return (t0 + t1) + (t2 + t3);
}

// ---- K2: fused MX-scaled fp8 GEMM + lse-pool. R13 structure (converged:
// gemm 53.5us, MfmaUtil 39). R13's distance-2 asm V pipeline ruled out V
// latency as the gap; per-SIMD pipe sums (MFMA 53k + VALU/TRANS ~47k + LDS
// 37k cy vs 128k wall) show a multi-pipe overlap limit with no single lever.
// Only change vs R13: V addresses read the unified 1-KB-unit layout
// (+0/+1024 instead of +0/+16) — same instruction count, same fragments.
__global__ __launch_bounds__(256, 2) void gemm_lse_kernel(
        const unsigned char* __restrict__ a8,
        const unsigned char* __restrict__ b8,
        float* __restrict__ out)
{
    __shared__ unsigned char ldsA[48 * 1024];   // block's 4 A-groups, whole K
    __shared__ float ms[4][4][32];              // [v-quarter][a-group][row]

    const int tid  = threadIdx.x;
    const int lane = tid & 63;
    const int wn   = tid >> 6;       // 4 waves = 4 v-quarters (64 v each)

    // XCD-chunked decode: bi tied to blockIdx%8 => per-XCD L2 set =
    // A(4 bi) 786KB + V(all) 3.1MB ~= 3.9MB <= 4MB.
    int b = blockIdx.x;
    const int xcd   = b & 7;      b >>= 3;
    const int bi_lo = b & 3;      b >>= 2;
    const int rb    = b & 3;      b >>= 2;   // row-block: 128 audio rows
    const int bj    = b;                      // 0..31
    const int bi    = xcd * 4 + bi_lo;        // 0..31

    // ---- stage A once: 48 KB (groups bi*16+rb*4 .. +3); wave wn stages group wn ----
    {
        const unsigned char* gsrc = a8 + (size_t)(bi * 16 + rb * 4 + wn) * GROUP_BYTES
                                       + (size_t)lane * 16;
        unsigned char* ldst = ldsA + (size_t)wn * GROUP_BYTES;
        #pragma unroll
        for (int kc = 0; kc < 12; ++kc)
            async_load16(gsrc + (size_t)kc * 1024, ldst + kc * 1024);
    }

    const unsigned char* pv0 = b8 + (size_t)(bj * 8 + wn * 2) * GROUP_BYTES
                                  + (size_t)lane * 16;
    const unsigned char* pv1 = pv0 + GROUP_BYTES;

    // ---- V register pipeline: slots 0..2, chunk c -> slot c%3, 4 loads/chunk.
    // chunk c = units 2c (lo 16B, +0) and 2c+1 (hi 16B, +1024).
    // Prologue: issue chunks 0 and 1 BEFORE __syncthreads (the sync drains
    // vmcnt(0) so both are resident at loop start; in-loop waits use the
    // steady-state count).
    int4v Vb[3][2][2];   // [slot][v-group][k-half] — all indices constant
    VLOAD16(Vb[0][0][0], pv0);
    VLOAD16(Vb[0][0][1], pv0 + 1024);
    VLOAD16(Vb[0][1][0], pv1);
    VLOAD16(Vb[0][1][1], pv1 + 1024);
    VLOAD16(Vb[1][0][0], pv0 + 2048);
    VLOAD16(Vb[1][0][1], pv0 + 2048 + 1024);
    VLOAD16(Vb[1][1][0], pv1 + 2048);
    VLOAD16(Vb[1][1][1], pv1 + 2048 + 1024);

    __syncthreads();   // A visible to all waves (also drains V chunks 0,1 — OK)

    const unsigned char* la = ldsA + (size_t)lane * 16;

    floatx16 acc[4][2];   // [audio group][v group]
    #pragma unroll
    for (int g = 0; g < 4; ++g)
        #pragma unroll
        for (int vg = 0; vg < 2; ++vg)
            acc[g][vg] = (floatx16)(0.0f);

    #pragma unroll
    for (int q2 = 0; q2 < NK2; ++q2) {
        // A: 4 groups' k64 operands from LDS (8 lane-contiguous ds_read_b128;
        // compiler emits counted lgkmcnt before first use)
        int8v A[4];
        #pragma unroll
        for (int g = 0; g < 4; ++g) {
            const unsigned char* p = la + (size_t)g * GROUP_BYTES + (size_t)q2 * 2048;
            int4v lo = *(const int4v*)p;
            int4v hi = *(const int4v*)(p + 1024);
            A[g] = __builtin_shufflevector(lo, hi, 0, 1, 2, 3, 4, 5, 6, 7);
        }
        // issue chunk q2+2's V loads into the slot freed at iter q2-1
        if (q2 + 2 < NK2) {
            const int s = (q2 + 2) % 3;
            const unsigned char* np0 = pv0 + (size_t)(q2 + 2) * 2048;
            const unsigned char* np1 = pv1 + (size_t)(q2 + 2) * 2048;
            VLOAD16(Vb[s][0][0], np0);
            VLOAD16(Vb[s][0][1], np0 + 1024);
            VLOAD16(Vb[s][1][0], np1);
            VLOAD16(Vb[s][1][1], np1 + 1024);
        }
        // counted wait: everything except the newest 8 loads (chunks q2+1,q2+2)
        // is complete => chunk q2 resident. Never 0 mid-loop.
        if (q2 + 2 < NK2)      { asm volatile("s_waitcnt vmcnt(8)"); }
        else if (q2 + 1 < NK2) { asm volatile("s_waitcnt vmcnt(4)"); }
        else                   { asm volatile("s_waitcnt vmcnt(0)"); }
        __builtin_amdgcn_sched_barrier(0);   // fence: consumers stay BELOW

        const int cs = q2 % 3;
        int8v V0 = __builtin_shufflevector(Vb[cs][0][0], Vb[cs][0][1],
                                           0, 1, 2, 3, 4, 5, 6, 7);
        int8v V1 = __builtin_shufflevector(Vb[cs][1][0], Vb[cs][1][1],
                                           0, 1, 2, 3, 4, 5, 6, 7);

        // 8 MFMAs, 8 independent acc chains; V regs reused 4x, A regs 2x
        __builtin_amdgcn_s_setprio(1);
        #pragma unroll
        for (int g = 0; g < 4; ++g) {
            acc[g][0] = __builtin_amdgcn_mfma_scale_f32_32x32x64_f8f6f4(
                V0, A[g], acc[g][0], 0, 0, 0, SCALE_ONE, 0, SCALE_ONE);
            acc[g][1] = __builtin_amdgcn_mfma_scale_f32_32x32x64_f8f6f4(
                V1, A[g], acc[g][1], 0, 0, 0, SCALE_ONE, 0, SCALE_ONE);
        }
        __builtin_amdgcn_s_setprio(0);
    }

    // ---- epilogue: per-thread exp-sum over this wave's 64 v ----
    // C/D layout (shape-determined): audio row = lane&31 within a-group;
    // regs & lane>>5 = v indices. (no max: |sims/tau| <= ~55 -> exact)
    float s[4];
    #pragma unroll
    for (int g = 0; g < 4; ++g) {
        s[g] = expsum16(acc[g][0]) + expsum16(acc[g][1]);
        s[g] += __shfl_xor(s[g], 32);   // merge lane>>5 v-halves
    }
    if (lane < 32) {
        #pragma unroll
        for (int g = 0; g < 4; ++g)
            ms[wn][g][lane] = s[g];
    }
    __syncthreads();

    // merge the 4 v-quarters (exp-space, linear -> exact), then lse + mean.
    // 128 block rows handled by 2 waves; one atomic per reducer wave.
    if (tid < 128) {
        const int g = tid >> 5, r = tid & 31;
        float e = (ms[0][g][r] + ms[1][g][r]) + (ms[2][g][r] + ms[3][g][r]);
        constexpr float TAU_LN2 = 1.3862943611198906f;  // tau*ln2 (v_log = log2)
        float lse = TAU_LN2 * __builtin_amdgcn_logf(e);
        #pragma unroll
        for (int m = 1; m < 64; m <<= 1) lse += __shfl_xor(lse, m);
        if ((tid & 63) == 0)
            atomicAdd(&out[bi * 32 + bj], lse * (1.0f / Na));  // 4rb x 2 = 8 adds
    }
}

extern "C" void kernel_launch(void* const* d_in, const int* in_sizes, int n_in,
                              void* d_out, int out_size, void* d_ws, size_t ws_size,
                              hipStream_t stream) {
    const float* audio  = (const float*)d_in[0];
    const float* visual = (const float*)d_in[1];
    float* out = (float*)d_out;

    unsigned char* a8 = (unsigned char*)d_ws;                        // 6.29 MB fp8 A
    unsigned char* b8 = a8 + (size_t)AGROUPS * GROUP_BYTES;          // +3.15 MB fp8 B

    convert_fp8_kernel<<<dim3((AGROUPS + BGROUPS) * 3), dim3(256), 0, stream>>>(
        audio, visual, a8, b8, out);
    // grid: 4096 blocks x 4 waves = 16384 waves
    //     = 32 bi x 32 bj x 4 row-blocks, block = 128 audio rows x 256 v
    gemm_lse_kernel<<<dim3(4096), dim3(256), 0, stream>>>(a8, b8, out);
}

// Round 15
// 124.792 us; speedup vs baseline: 1.0149x; 1.0149x over previous
//
#include <hip/hip_runtime.h>

// ---- problem constants (fixed by reference setup_inputs) ----
constexpr int B_  = 32;
constexpr int Na  = 512;
constexpr int Nv  = 256;
constexpr int D   = 384;

constexpr int NK2 = D / 64;    // 6 k-chunks of 64 (one scaled MFMA each)

// fp8 operand regions, one 32-row group x 384 k = 12 KB per group.
// UNIFIED layout both sides: unit kc (1 KB): byte = h2*512 + r*16 + j holding
//   value[row r][k = kc*32 + h2*16 + j]; MFMA lane l reads 16 B at l*16
//   (r = l&31, h2 = l>>5). K=64 operand = unit 2q2 (regs0-3) + unit 2q2+1
//   (regs4-7): two 16B loads at +0 / +1024.
// The (lane,byte)->k packing is IDENTICAL for A-slot and B-slot operands,
// so the contraction is exact under operand swap; scales = 1.0 (e8m0 0x7F)
// make the scaled MFMA numerically identical to non-scaled fp8.
constexpr int AGROUPS = B_ * 16;   // 512 groups (bi*16+rg), rows linear
constexpr int BGROUPS = B_ * 8;    // 256 groups (bj*8+cg), rows linear
constexpr size_t GROUP_BYTES = 12 * 1024;
constexpr int SCALE_ONE = 0x7F7F7F7F;   // e8m0 127 = 2^0 in every byte

typedef int   int4v    __attribute__((ext_vector_type(4)));
typedef int   int8v    __attribute__((ext_vector_type(8)));
typedef float floatx16 __attribute__((ext_vector_type(16)));

// 16B-per-lane async global->LDS (lane i writes LDS slot base + i*16)
__device__ __forceinline__ void async_load16(const void* g, void* l) {
    __builtin_amdgcn_global_load_lds(
        (const __attribute__((address_space(1))) unsigned int*)g,
        (__attribute__((address_space(3))) unsigned int*)l,
        16, 0, 0);
}

// asm-volatile global load: UNSINKABLE by the scheduler (plain C++ "prefetch"
// loads get sunk to their use — R3's VGPR=104 proved it). Completion is NOT
// compiler-tracked: consumers sit after an explicit counted s_waitcnt +
// sched_barrier(0) fence (rule #18).
#define VLOAD16(dst, ptr) \
    asm volatile("global_load_dwordx4 %0, %1, off" : "=v"(dst) : "v"(ptr))

// ---- K1: zero output + fp32 -> fp8(e4m3 OCP) conversion, BOTH sides coalesced ----
// R15: REVERT to the R0/R9 form — 768 blocks, 3 serial passes/thread.
// Session ledger: 3-pass/768-block K1 => non-gemm 60-63.5us (R0-R4, R9);
// R10's "3x TLP" 1-pass/2304-block split => 66.8-73.5us. The split REGRESSED
// ~8us (3x per-block dispatch/ramp cost; the 3 serial passes were already
// latency-covered by 12 waves/SIMD TLP). Per pass a wave's 64 stores tile
// 16 full 64-B lines; reads are 8x512B contiguous row-chunks.
__global__ void convert_fp8_kernel(const float* __restrict__ a, const float* __restrict__ v,
                                   unsigned char* __restrict__ a8,
                                   unsigned char* __restrict__ b8,
                                   float* __restrict__ out) {
    int gid = blockIdx.x * blockDim.x + threadIdx.x;
    if (gid < B_ * B_) out[gid] = 0.0f;    // d_out is poisoned before every launch

    const float* src;
    unsigned char* dst;
    int blk = blockIdx.x;
    if (blk < AGROUPS) {                       // A rows are linear: group*32 + r
        src = a + (size_t)blk * 32 * D;
        dst = a8 + (size_t)blk * GROUP_BYTES;
    } else {
        int b2 = blk - AGROUPS;
        src = v + (size_t)b2 * 32 * D;
        dst = b8 + (size_t)b2 * GROUP_BYTES;
    }
    const int t = threadIdx.x;
    const int r = t >> 3, q = t & 7;

    #pragma unroll
    for (int p = 0; p < 3; ++p) {
        int k0 = p * 128 + q * 16;
        const float4* s4 = (const float4*)(src + (size_t)r * D + k0);
        float4 f0 = s4[0], f1 = s4[1], f2 = s4[2], f3 = s4[3];
        int w0 = 0, w1 = 0, w2 = 0, w3 = 0;
        w0 = __builtin_amdgcn_cvt_pk_fp8_f32(f0.x, f0.y, w0, false);
        w0 = __builtin_amdgcn_cvt_pk_fp8_f32(f0.z, f0.w, w0, true);
        w1 = __builtin_amdgcn_cvt_pk_fp8_f32(f1.x, f1.y, w1, false);
        w1 = __builtin_amdgcn_cvt_pk_fp8_f32(f1.z, f1.w, w1, true);
        w2 = __builtin_amdgcn_cvt_pk_fp8_f32(f2.x, f2.y, w2, false);
        w2 = __builtin_amdgcn_cvt_pk_fp8_f32(f2.z, f2.w, w2, true);
        w3 = __builtin_amdgcn_cvt_pk_fp8_f32(f3.x, f3.y, w3, false);
        w3 = __builtin_amdgcn_cvt_pk_fp8_f32(f3.z, f3.w, w3, true);
        int kc = k0 >> 5;
        int h2 = (k0 >> 4) & 1;
        int4v o = { w0, w1, w2, w3 };
        *(int4v*)(dst + (size_t)kc * 1024 + h2 * 512 + r * 16) = o;
    }
}

// sum of exp2(a[i] * 1/(tau*ln2)) over one accumulator, pairwise tree.
// RAW v_exp_f32: |x| <= ~60, inside the exact range of the HW instruction.
__device__ __forceinline__ float expsum16(floatx16 a) {
    constexpr float INV_TAU_LN2 = 0.7213475204444817f;  // 1/(tau*ln2), tau=2
    float e[16];
    #pragma unroll
    for (int i = 0; i < 16; ++i)
        e[i] = __builtin_amdgcn_exp2f(a[i] * INV_TAU_LN2);
    float t0 = (e[0] + e[1])  + (e[2] + e[3]);
    float t1 = (e[4] + e[5])  + (e[6] + e[7]);
    float t2 = (e[8] + e[9])  + (e[10] + e[11]);
    float t3 = (e[12] + e[13]) + (e[14] + e[15]);
    return (t0 + t1) + (t2 + t3);
}

// ---- K2: fused MX-scaled fp8 GEMM + lse-pool. R13/R14 structure, UNCHANGED
// (converged: gemm 53.1us, MfmaUtil ~39). Six independent delivery structures
// (direct-global / LDS-A / all-LDS / counted-vmcnt template / asm distance-2
// pipeline) all pinned at 53-58us — multi-pipe overlap limit, no single lever.
__global__ __launch_bounds__(256, 2) void gemm_lse_kernel(
        const unsigned char* __restrict__ a8,
        const unsigned char* __restrict__ b8,
        float* __restrict__ out)
{
    __shared__ unsigned char ldsA[48 * 1024];   // block's 4 A-groups, whole K
    __shared__ float ms[4][4][32];              // [v-quarter][a-group][row]

    const int tid  = threadIdx.x;
    const int lane = tid & 63;
    const int wn   = tid >> 6;       // 4 waves = 4 v-quarters (64 v each)

    // XCD-chunked decode: bi tied to blockIdx%8 => per-XCD L2 set =
    // A(4 bi) 786KB + V(all) 3.1MB ~= 3.9MB <= 4MB.
    int b = blockIdx.x;
    const int xcd   = b & 7;      b >>= 3;
    const int bi_lo = b & 3;      b >>= 2;
    const int rb    = b & 3;      b >>= 2;   // row-block: 128 audio rows
    const int bj    = b;                      // 0..31
    const int bi    = xcd * 4 + bi_lo;        // 0..31

    // ---- stage A once: 48 KB (groups bi*16+rb*4 .. +3); wave wn stages group wn ----
    {
        const unsigned char* gsrc = a8 + (size_t)(bi * 16 + rb * 4 + wn) * GROUP_BYTES
                                       + (size_t)lane * 16;
        unsigned char* ldst = ldsA + (size_t)wn * GROUP_BYTES;
        #pragma unroll
        for (int kc = 0; kc < 12; ++kc)
            async_load16(gsrc + (size_t)kc * 1024, ldst + kc * 1024);
    }

    const unsigned char* pv0 = b8 + (size_t)(bj * 8 + wn * 2) * GROUP_BYTES
                                  + (size_t)lane * 16;
    const unsigned char* pv1 = pv0 + GROUP_BYTES;

    // ---- V register pipeline: slots 0..2, chunk c -> slot c%3, 4 loads/chunk.
    // chunk c = units 2c (lo 16B, +0) and 2c+1 (hi 16B, +1024).
    // Prologue: issue chunks 0 and 1 BEFORE __syncthreads (the sync drains
    // vmcnt(0) so both are resident at loop start).
    int4v Vb[3][2][2];   // [slot][v-group][k-half] — all indices constant
    VLOAD16(Vb[0][0][0], pv0);
    VLOAD16(Vb[0][0][1], pv0 + 1024);
    VLOAD16(Vb[0][1][0], pv1);
    VLOAD16(Vb[0][1][1], pv1 + 1024);
    VLOAD16(Vb[1][0][0], pv0 + 2048);
    VLOAD16(Vb[1][0][1], pv0 + 2048 + 1024);
    VLOAD16(Vb[1][1][0], pv1 + 2048);
    VLOAD16(Vb[1][1][1], pv1 + 2048 + 1024);

    __syncthreads();   // A visible to all waves (also drains V chunks 0,1 — OK)

    const unsigned char* la = ldsA + (size_t)lane * 16;

    floatx16 acc[4][2];   // [audio group][v group]
    #pragma unroll
    for (int g = 0; g < 4; ++g)
        #pragma unroll
        for (int vg = 0; vg < 2; ++vg)
            acc[g][vg] = (floatx16)(0.0f);

    #pragma unroll
    for (int q2 = 0; q2 < NK2; ++q2) {
        // A: 4 groups' k64 operands from LDS (8 lane-contiguous ds_read_b128;
        // compiler emits counted lgkmcnt before first use)
        int8v A[4];
        #pragma unroll
        for (int g = 0; g < 4; ++g) {
            const unsigned char* p = la + (size_t)g * GROUP_BYTES + (size_t)q2 * 2048;
            int4v lo = *(const int4v*)p;
            int4v hi = *(const int4v*)(p + 1024);
            A[g] = __builtin_shufflevector(lo, hi, 0, 1, 2, 3, 4, 5, 6, 7);
        }
        // issue chunk q2+2's V loads into the slot freed at iter q2-1
        if (q2 + 2 < NK2) {
            const int s = (q2 + 2) % 3;
            const unsigned char* np0 = pv0 + (size_t)(q2 + 2) * 2048;
            const unsigned char* np1 = pv1 + (size_t)(q2 + 2) * 2048;
            VLOAD16(Vb[s][0][0], np0);
            VLOAD16(Vb[s][0][1], np0 + 1024);
            VLOAD16(Vb[s][1][0], np1);
            VLOAD16(Vb[s][1][1], np1 + 1024);
        }
        // counted wait: everything except the newest 8 loads (chunks q2+1,q2+2)
        // is complete => chunk q2 resident. Never 0 mid-loop.
        if (q2 + 2 < NK2)      { asm volatile("s_waitcnt vmcnt(8)"); }
        else if (q2 + 1 < NK2) { asm volatile("s_waitcnt vmcnt(4)"); }
        else                   { asm volatile("s_waitcnt vmcnt(0)"); }
        __builtin_amdgcn_sched_barrier(0);   // fence: consumers stay BELOW

        const int cs = q2 % 3;
        int8v V0 = __builtin_shufflevector(Vb[cs][0][0], Vb[cs][0][1],
                                           0, 1, 2, 3, 4, 5, 6, 7);
        int8v V1 = __builtin_shufflevector(Vb[cs][1][0], Vb[cs][1][1],
                                           0, 1, 2, 3, 4, 5, 6, 7);

        // 8 MFMAs, 8 independent acc chains; V regs reused 4x, A regs 2x
        __builtin_amdgcn_s_setprio(1);
        #pragma unroll
        for (int g = 0; g < 4; ++g) {
            acc[g][0] = __builtin_amdgcn_mfma_scale_f32_32x32x64_f8f6f4(
                V0, A[g], acc[g][0], 0, 0, 0, SCALE_ONE, 0, SCALE_ONE);
            acc[g][1] = __builtin_amdgcn_mfma_scale_f32_32x32x64_f8f6f4(
                V1, A[g], acc[g][1], 0, 0, 0, SCALE_ONE, 0, SCALE_ONE);
        }
        __builtin_amdgcn_s_setprio(0);
    }

    // ---- epilogue: per-thread exp-sum over this wave's 64 v ----
    // C/D layout (shape-determined): audio row = lane&31 within a-group;
    // regs & lane>>5 = v indices. (no max: |sims/tau| <= ~55 -> exact)
    float s[4];
    #pragma unroll
    for (int g = 0; g < 4; ++g) {
        s[g] = expsum16(acc[g][0]) + expsum16(acc[g][1]);
        s[g] += __shfl_xor(s[g], 32);   // merge lane>>5 v-halves
    }
    if (lane < 32) {
        #pragma unroll
        for (int g = 0; g < 4; ++g)
            ms[wn][g][lane] = s[g];
    }
    __syncthreads();

    // merge the 4 v-quarters (exp-space, linear -> exact), then lse + mean.
    // 128 block rows handled by 2 waves; one atomic per reducer wave.
    if (tid < 128) {
        const int g = tid >> 5, r = tid & 31;
        float e = (ms[0][g][r] + ms[1][g][r]) + (ms[2][g][r] + ms[3][g][r]);
        constexpr float TAU_LN2 = 1.3862943611198906f;  // tau*ln2 (v_log = log2)
        float lse = TAU_LN2 * __builtin_amdgcn_logf(e);
        #pragma unroll
        for (int m = 1; m < 64; m <<= 1) lse += __shfl_xor(lse, m);
        if ((tid & 63) == 0)
            atomicAdd(&out[bi * 32 + bj], lse * (1.0f / Na));  // 4rb x 2 = 8 adds
    }
}

extern "C" void kernel_launch(void* const* d_in, const int* in_sizes, int n_in,
                              void* d_out, int out_size, void* d_ws, size_t ws_size,
                              hipStream_t stream) {
    const float* audio  = (const float*)d_in[0];
    const float* visual = (const float*)d_in[1];
    float* out = (float*)d_out;

    unsigned char* a8 = (unsigned char*)d_ws;                        // 6.29 MB fp8 A
    unsigned char* b8 = a8 + (size_t)AGROUPS * GROUP_BYTES;          // +3.15 MB fp8 B

    // 768 blocks, 3 passes/thread (R0/R9 form — measured best K1 config)
    convert_fp8_kernel<<<dim3(AGROUPS + BGROUPS), dim3(256), 0, stream>>>(
        audio, visual, a8, b8, out);
    // grid: 4096 blocks x 4 waves = 16384 waves
    //     = 32 bi x 32 bj x 4 row-blocks, block = 128 audio rows x 256 v
    gemm_lse_kernel<<<dim3(4096), dim3(256), 0, stream>>>(a8, b8, out);
}